// Round 3
// baseline (249.622 us; speedup 1.0000x reference)
//
#include <hip/hip_runtime.h>

// GradeWiseLinear: x (8,2048,128,16) f32, block-diagonal linear over last dim,
// grade dims {1,4,6,4,1}. Memory-bound: 268 MB traffic, copy-roofline ~43 us.
//
// R3: one float4 (quarter-row) per lane, neighbor values via intra-wave
// shuffles (rows of 4 chunks never straddle a wave), so memory traffic is
// exactly 1 aligned load + 1 aligned store per lane (pure-copy pattern).
// Nontemporal load/store: every byte touched exactly once, skip cache fill.

typedef float v4f __attribute__((ext_vector_type(4)));

__global__ __launch_bounds__(256) void GradeWiseLinear_kernel(
    const float* __restrict__ x,
    const float* __restrict__ w0, const float* __restrict__ b0,
    const float* __restrict__ w1, const float* __restrict__ b1,
    const float* __restrict__ w2, const float* __restrict__ b2,
    const float* __restrict__ w3, const float* __restrict__ b3,
    const float* __restrict__ w4, const float* __restrict__ b4,
    float* __restrict__ out, int n4)
{
    // Packed LDS weights/biases (wave-uniform broadcast reads, conflict-free):
    // [0] w0 | [1..16] w1 | [17..52] w2 | [53..68] w3 | [69] w4 | [70..85] biases
    __shared__ float s[86];
    {
        int t = threadIdx.x;
        if (t < 86) {
            float v;
            if      (t == 0)  v = w0[0];
            else if (t < 17)  v = w1[t - 1];
            else if (t < 53)  v = w2[t - 17];
            else if (t < 69)  v = w3[t - 53];
            else if (t == 69) v = w4[0];
            else if (t == 70) v = b0[0];
            else if (t < 75)  v = b1[t - 71];
            else if (t < 81)  v = b2[t - 75];
            else if (t < 85)  v = b3[t - 81];
            else              v = b4[0];
            s[t] = v;
        }
    }
    __syncthreads();

    int g = blockIdx.x * 256 + threadIdx.x;   // float4 chunk index
    if (g >= n4) return;

    const int j = g & 3;                      // chunk-in-row (0..3)

    v4f me = __builtin_nontemporal_load((const v4f*)x + g);

    // Neighbor chunk values via intra-wave shuffles (lane +/- 1).
    // j==0 lane never uses up*, j==3 lane never uses dn*.
    float up_y = __shfl_up(me.y, 1);
    float up_z = __shfl_up(me.z, 1);
    float up_w = __shfl_up(me.w, 1);
    float dn_x = __shfl_down(me.x, 1);
    float dn_y = __shfl_down(me.y, 1);
    float dn_z = __shfl_down(me.z, 1);

    float o0, o1, o2, o3;

    if (j == 0) {
        // out0 = b0 + x0*w0 ; out1..3 = b1[0..2] + W1[0..2] . x[1..4]
        o0 = s[70] + me.x * s[0];
        o1 = s[71] + me.y * s[1] + me.z * s[2]  + me.w * s[3]  + dn_x * s[4];
        o2 = s[72] + me.y * s[5] + me.z * s[6]  + me.w * s[7]  + dn_x * s[8];
        o3 = s[73] + me.y * s[9] + me.z * s[10] + me.w * s[11] + dn_x * s[12];
    } else if (j == 1) {
        // out4 = b1[3] + W1[3] . x[1..4]
        o0 = s[74] + up_y * s[13] + up_z * s[14] + up_w * s[15] + me.x * s[16];
        // out5..7 = b2[0..2] + W2[0..2] . x[5..10]
        o1 = s[75] + me.y * s[17] + me.z * s[18] + me.w * s[19]
                   + dn_x * s[20] + dn_y * s[21] + dn_z * s[22];
        o2 = s[76] + me.y * s[23] + me.z * s[24] + me.w * s[25]
                   + dn_x * s[26] + dn_y * s[27] + dn_z * s[28];
        o3 = s[77] + me.y * s[29] + me.z * s[30] + me.w * s[31]
                   + dn_x * s[32] + dn_y * s[33] + dn_z * s[34];
    } else if (j == 2) {
        // out8..10 = b2[3..5] + W2[3..5] . x[5..10]
        o0 = s[78] + up_y * s[35] + up_z * s[36] + up_w * s[37]
                   + me.x * s[38] + me.y * s[39] + me.z * s[40];
        o1 = s[79] + up_y * s[41] + up_z * s[42] + up_w * s[43]
                   + me.x * s[44] + me.y * s[45] + me.z * s[46];
        o2 = s[80] + up_y * s[47] + up_z * s[48] + up_w * s[49]
                   + me.x * s[50] + me.y * s[51] + me.z * s[52];
        // out11 = b3[0] + W3[0] . x[11..14]
        o3 = s[81] + me.w * s[53] + dn_x * s[54] + dn_y * s[55] + dn_z * s[56];
    } else {
        // out12..14 = b3[1..3] + W3[1..3] . x[11..14]
        o0 = s[82] + up_w * s[57] + me.x * s[58] + me.y * s[59] + me.z * s[60];
        o1 = s[83] + up_w * s[61] + me.x * s[62] + me.y * s[63] + me.z * s[64];
        o2 = s[84] + up_w * s[65] + me.x * s[66] + me.y * s[67] + me.z * s[68];
        // out15 = b4 + x15*w4
        o3 = s[85] + me.w * s[69];
    }

    v4f r; r.x = o0; r.y = o1; r.z = o2; r.w = o3;
    __builtin_nontemporal_store(r, (v4f*)out + g);
}

extern "C" void kernel_launch(void* const* d_in, const int* in_sizes, int n_in,
                              void* d_out, int out_size, void* d_ws, size_t ws_size,
                              hipStream_t stream) {
    const float* x  = (const float*)d_in[0];
    const float* w0 = (const float*)d_in[1];
    const float* b0 = (const float*)d_in[2];
    const float* w1 = (const float*)d_in[3];
    const float* b1 = (const float*)d_in[4];
    const float* w2 = (const float*)d_in[5];
    const float* b2 = (const float*)d_in[6];
    const float* w3 = (const float*)d_in[7];
    const float* b3 = (const float*)d_in[8];
    const float* w4 = (const float*)d_in[9];
    const float* b4 = (const float*)d_in[10];
    float* out = (float*)d_out;

    int n4 = in_sizes[0] / 4;               // 8,388,608 float4 chunks
    int block = 256;
    int grid = (n4 + block - 1) / block;    // 32768

    GradeWiseLinear_kernel<<<grid, block, 0, stream>>>(
        x, w0, b0, w1, b1, w2, b2, w3, b3, w4, b4, out, n4);
}

// Round 4
// 248.061 us; speedup vs baseline: 1.0063x; 1.0063x over previous
//
#include <hip/hip_runtime.h>

// GradeWiseLinear: x (8,2048,128,16) f32, block-diagonal linear over last dim,
// grade dims {1,4,6,4,1}. Memory-bound: 268 MB traffic, copy-roofline ~43 us.
//
// R4: 4 float4 chunks per lane (stride 256 within a 1024-chunk block) for
// 4x memory-level parallelism; neighbor elements via intra-wave shuffles;
// regular loads (input is L3-resident from the harness restore), nontemporal
// stores (keep output streaming from evicting the input from L3).

typedef float v4f __attribute__((ext_vector_type(4)));

__global__ __launch_bounds__(256) void GradeWiseLinear_kernel(
    const float* __restrict__ x,
    const float* __restrict__ w0, const float* __restrict__ b0,
    const float* __restrict__ w1, const float* __restrict__ b1,
    const float* __restrict__ w2, const float* __restrict__ b2,
    const float* __restrict__ w3, const float* __restrict__ b3,
    const float* __restrict__ w4, const float* __restrict__ b4,
    float* __restrict__ out, int n4)
{
    // Packed LDS weights/biases (wave-uniform broadcast reads, conflict-free):
    // [0] w0 | [1..16] w1 | [17..52] w2 | [53..68] w3 | [69] w4 | [70..85] biases
    __shared__ float s[86];
    {
        int t = threadIdx.x;
        if (t < 86) {
            float v;
            if      (t == 0)  v = w0[0];
            else if (t < 17)  v = w1[t - 1];
            else if (t < 53)  v = w2[t - 17];
            else if (t < 69)  v = w3[t - 53];
            else if (t == 69) v = w4[0];
            else if (t == 70) v = b0[0];
            else if (t < 75)  v = b1[t - 71];
            else if (t < 81)  v = b2[t - 75];
            else if (t < 85)  v = b3[t - 81];
            else              v = b4[0];
            s[t] = v;
        }
    }
    __syncthreads();

    const int t = threadIdx.x;
    const int base = blockIdx.x * 1024 + t;   // chunk index of batch 0
    const int j = t & 3;                      // chunk-in-row role (0..3), same for all 4 batches

    const v4f* xv = (const v4f*)x;

    // Issue all 4 independent loads first (4 KiB in flight per wave).
    v4f me[4];
    #pragma unroll
    for (int k = 0; k < 4; ++k) me[k] = xv[base + 256 * k];

    // Neighbor chunk values via intra-wave shuffles. For chunk base+256k+t the
    // +/-1 chunk lives on lane t-/+1 (same batch k). Lanes with j>0 always have
    // (t%64)>=1 and j<3 implies (t%64)<=62, so shuffles never cross the wave.
    float up_y[4], up_z[4], up_w[4], dn_x[4], dn_y[4], dn_z[4];
    #pragma unroll
    for (int k = 0; k < 4; ++k) {
        up_y[k] = __shfl_up(me[k].y, 1);
        up_z[k] = __shfl_up(me[k].z, 1);
        up_w[k] = __shfl_up(me[k].w, 1);
        dn_x[k] = __shfl_down(me[k].x, 1);
        dn_y[k] = __shfl_down(me[k].y, 1);
        dn_z[k] = __shfl_down(me[k].z, 1);
    }

    v4f r[4];

    if (j == 0) {
        #pragma unroll
        for (int k = 0; k < 4; ++k) {
            r[k].x = s[70] + me[k].x * s[0];
            r[k].y = s[71] + me[k].y * s[1] + me[k].z * s[2]  + me[k].w * s[3]  + dn_x[k] * s[4];
            r[k].z = s[72] + me[k].y * s[5] + me[k].z * s[6]  + me[k].w * s[7]  + dn_x[k] * s[8];
            r[k].w = s[73] + me[k].y * s[9] + me[k].z * s[10] + me[k].w * s[11] + dn_x[k] * s[12];
        }
    } else if (j == 1) {
        #pragma unroll
        for (int k = 0; k < 4; ++k) {
            r[k].x = s[74] + up_y[k] * s[13] + up_z[k] * s[14] + up_w[k] * s[15] + me[k].x * s[16];
            r[k].y = s[75] + me[k].y * s[17] + me[k].z * s[18] + me[k].w * s[19]
                           + dn_x[k] * s[20] + dn_y[k] * s[21] + dn_z[k] * s[22];
            r[k].z = s[76] + me[k].y * s[23] + me[k].z * s[24] + me[k].w * s[25]
                           + dn_x[k] * s[26] + dn_y[k] * s[27] + dn_z[k] * s[28];
            r[k].w = s[77] + me[k].y * s[29] + me[k].z * s[30] + me[k].w * s[31]
                           + dn_x[k] * s[32] + dn_y[k] * s[33] + dn_z[k] * s[34];
        }
    } else if (j == 2) {
        #pragma unroll
        for (int k = 0; k < 4; ++k) {
            r[k].x = s[78] + up_y[k] * s[35] + up_z[k] * s[36] + up_w[k] * s[37]
                           + me[k].x * s[38] + me[k].y * s[39] + me[k].z * s[40];
            r[k].y = s[79] + up_y[k] * s[41] + up_z[k] * s[42] + up_w[k] * s[43]
                           + me[k].x * s[44] + me[k].y * s[45] + me[k].z * s[46];
            r[k].z = s[80] + up_y[k] * s[47] + up_z[k] * s[48] + up_w[k] * s[49]
                           + me[k].x * s[50] + me[k].y * s[51] + me[k].z * s[52];
            r[k].w = s[81] + me[k].w * s[53] + dn_x[k] * s[54] + dn_y[k] * s[55] + dn_z[k] * s[56];
        }
    } else {
        #pragma unroll
        for (int k = 0; k < 4; ++k) {
            r[k].x = s[82] + up_w[k] * s[57] + me[k].x * s[58] + me[k].y * s[59] + me[k].z * s[60];
            r[k].y = s[83] + up_w[k] * s[61] + me[k].x * s[62] + me[k].y * s[63] + me[k].z * s[64];
            r[k].z = s[84] + up_w[k] * s[65] + me[k].x * s[66] + me[k].y * s[67] + me[k].z * s[68];
            r[k].w = s[85] + me[k].w * s[69];
        }
    }

    v4f* ov = (v4f*)out;
    #pragma unroll
    for (int k = 0; k < 4; ++k)
        __builtin_nontemporal_store(r[k], ov + base + 256 * k);
}

extern "C" void kernel_launch(void* const* d_in, const int* in_sizes, int n_in,
                              void* d_out, int out_size, void* d_ws, size_t ws_size,
                              hipStream_t stream) {
    const float* x  = (const float*)d_in[0];
    const float* w0 = (const float*)d_in[1];
    const float* b0 = (const float*)d_in[2];
    const float* w1 = (const float*)d_in[3];
    const float* b1 = (const float*)d_in[4];
    const float* w2 = (const float*)d_in[5];
    const float* b2 = (const float*)d_in[6];
    const float* w3 = (const float*)d_in[7];
    const float* b3 = (const float*)d_in[8];
    const float* w4 = (const float*)d_in[9];
    const float* b4 = (const float*)d_in[10];
    float* out = (float*)d_out;

    int n4 = in_sizes[0] / 4;               // 8,388,608 float4 chunks
    int block = 256;
    int grid = n4 / (block * 4);            // 8192 blocks, 4 chunks/thread

    GradeWiseLinear_kernel<<<grid, block, 0, stream>>>(
        x, w0, b0, w1, b1, w2, b2, w3, b3, w4, b4, out, n4);
}